// Round 1
// baseline (691.636 us; speedup 1.0000x reference)
//
#include <hip/hip_runtime.h>
#include <stdint.h>

// BiDAF co-attention, B=8, L=4096, D=1024, M=2. All FP32.
// Restructured single-input-pass pipeline:
//   kP  : fold weights -> cvec[b][m][d] = w_in[d] + ds[d]*mem[b,m,d]; mdot[bm]
//   kA  : ONE pass over input. Per row: att, seg0=x, seg1=o1, seg2=x*o1.
//         Online-softmax-over-L accumulation of output_two numerator
//         (per-wave running max/Z/acc, block-combined in LDS -> partials).
//   kB  : combine 128 partials/batch -> normalized out2[b][d].
//   kE  : seg3 = out2 * o1 per row (reads only att/memory/out2 -> pure write).
// HBM traffic: 134 MB read + ~541 MB write + ~10 MB partials  (~minimum).

#define BB 8
#define LL 4096
#define DD 1024
#define BPB 128            // kA blocks per batch
#define RPB 32             // rows per kA block   (LL / BPB)
#define RPW 8              // rows per wave       (RPB / 4 waves)

// ---- kP: cvec[b][m][d] = w_input[d] + dot_scale[d]*mem[b,m,d]; mdot[bm] = <mem_bm, w_memory>
__global__ __launch_bounds__(256) void kP(const float* __restrict__ mem,
                                          const float* __restrict__ w_in,
                                          const float* __restrict__ w_mem,
                                          const float* __restrict__ ds,
                                          float* __restrict__ cvec,
                                          float* __restrict__ mdot) {
    int bm = blockIdx.x;            // 0..15
    int t  = threadIdx.x;           // 256
    const float* mrow = mem + bm * DD;
    float partial = 0.f;
#pragma unroll
    for (int j = 0; j < 4; ++j) {
        int d = t * 4 + j;
        float m = mrow[d];
        cvec[bm * DD + d] = fmaf(ds[d], m, w_in[d]);
        partial = fmaf(m, w_mem[d], partial);
    }
    __shared__ float red[4];
    for (int off = 32; off; off >>= 1) partial += __shfl_down(partial, off);
    if ((t & 63) == 0) red[t >> 6] = partial;
    __syncthreads();
    if (t == 0) mdot[bm] = red[0] + red[1] + red[2] + red[3];
}

// ---- kA: single input pass. 1024 blocks (128/batch), 4 waves/block, 8 rows/wave.
__global__ __launch_bounds__(256) void kA(const float* __restrict__ input,
                                          const float* __restrict__ memory,
                                          const float* __restrict__ cvec,
                                          const float* __restrict__ mdot,
                                          float* __restrict__ att,
                                          float* __restrict__ pmax,
                                          float* __restrict__ pz,
                                          float* __restrict__ pacc,
                                          float* __restrict__ out) {
    int blk = blockIdx.x;           // 1024
    int b = blk >> 7, chunk = blk & 127;
    int t = threadIdx.x;
    int wave = t >> 6, lane = t & 63;

    // row-invariant per-lane fragments: folded weights + memory rows
    const float4* c0p = (const float4*)(cvec + (size_t)b * 2 * DD);
    const float4* c1p = c0p + DD / 4;
    const float4* m0p = (const float4*)(memory + (size_t)b * 2 * DD);
    const float4* m1p = m0p + DD / 4;
    float4 rc0[4], rc1[4], rm0[4], rm1[4], acc[4];
#pragma unroll
    for (int k = 0; k < 4; ++k) {
        rc0[k] = c0p[lane + 64 * k];
        rc1[k] = c1p[lane + 64 * k];
        rm0[k] = m0p[lane + 64 * k];
        rm1[k] = m1p[lane + 64 * k];
        acc[k] = make_float4(0.f, 0.f, 0.f, 0.f);
    }
    float md0 = mdot[b * 2], md1 = mdot[b * 2 + 1];
    float lmax = -1e30f, zsum = 0.f;

    int l0 = chunk * RPB + wave * RPW;
    for (int r = 0; r < RPW; ++r) {
        int l = l0 + r;
        const float4* row = (const float4*)(input + (size_t)(b * LL + l) * DD);
        float4 x[4];
#pragma unroll
        for (int k = 0; k < 4; ++k) x[k] = row[lane + 64 * k];

        float a0 = 0.f, a1 = 0.f;
#pragma unroll
        for (int k = 0; k < 4; ++k) {
            a0 = fmaf(x[k].x, rc0[k].x, a0); a0 = fmaf(x[k].y, rc0[k].y, a0);
            a0 = fmaf(x[k].z, rc0[k].z, a0); a0 = fmaf(x[k].w, rc0[k].w, a0);
            a1 = fmaf(x[k].x, rc1[k].x, a1); a1 = fmaf(x[k].y, rc1[k].y, a1);
            a1 = fmaf(x[k].z, rc1[k].z, a1); a1 = fmaf(x[k].w, rc1[k].w, a1);
        }
        // butterfly: every lane gets the full row sums
        for (int off = 32; off; off >>= 1) {
            a0 += __shfl_xor(a0, off);
            a1 += __shfl_xor(a1, off);
        }
        a0 += md0; a1 += md1;
        if (lane == 0) ((float2*)att)[(size_t)b * LL + l] = make_float2(a0, a1);

        float w0 = 1.f / (1.f + __expf(a1 - a0));   // softmax over M=2
        float w1 = 1.f - w0;
        float ml = fmaxf(a0, a1);

        // online softmax over L (wave-uniform branch)
        float e;
        if (ml > lmax) {
            float s = __expf(lmax - ml);
            zsum *= s;
#pragma unroll
            for (int k = 0; k < 4; ++k) {
                acc[k].x *= s; acc[k].y *= s; acc[k].z *= s; acc[k].w *= s;
            }
            lmax = ml;
            e = 1.f;
        } else {
            e = __expf(ml - lmax);
        }
        zsum += e;

        float* orow = out + (size_t)(b * LL + l) * (4 * DD);
#pragma unroll
        for (int k = 0; k < 4; ++k) {
            float4 o1;
            o1.x = fmaf(w0, rm0[k].x, w1 * rm1[k].x);
            o1.y = fmaf(w0, rm0[k].y, w1 * rm1[k].y);
            o1.z = fmaf(w0, rm0[k].z, w1 * rm1[k].z);
            o1.w = fmaf(w0, rm0[k].w, w1 * rm1[k].w);
            ((float4*)orow)[lane + 64 * k] = x[k];                                   // seg0
            ((float4*)(orow + DD))[lane + 64 * k] = o1;                              // seg1
            ((float4*)(orow + 2 * DD))[lane + 64 * k] =
                make_float4(x[k].x * o1.x, x[k].y * o1.y,
                            x[k].z * o1.z, x[k].w * o1.w);                           // seg2
            acc[k].x = fmaf(e, x[k].x, acc[k].x);
            acc[k].y = fmaf(e, x[k].y, acc[k].y);
            acc[k].z = fmaf(e, x[k].z, acc[k].z);
            acc[k].w = fmaf(e, x[k].w, acc[k].w);
        }
    }

    // ---- block combine: 4 wave partials -> 1 block partial
    __shared__ float swm[4], swz[4];
    __shared__ __align__(16) float sacc[DD];
    if (lane == 0) { swm[wave] = lmax; swz[wave] = zsum; }   // wave-uniform values
    for (int j = t; j < DD; j += 256) sacc[j] = 0.f;
    __syncthreads();
    float bmax = fmaxf(fmaxf(swm[0], swm[1]), fmaxf(swm[2], swm[3]));
    float f = __expf(lmax - bmax);
#pragma unroll
    for (int k = 0; k < 4; ++k) {
        int idx = 4 * (lane + 64 * k);
        atomicAdd(&sacc[idx + 0], f * acc[k].x);
        atomicAdd(&sacc[idx + 1], f * acc[k].y);
        atomicAdd(&sacc[idx + 2], f * acc[k].z);
        atomicAdd(&sacc[idx + 3], f * acc[k].w);
    }
    __syncthreads();
    if (t == 0) {
        float bz = 0.f;
#pragma unroll
        for (int w = 0; w < 4; ++w) bz += swz[w] * __expf(swm[w] - bmax);
        pmax[blk] = bmax;
        pz[blk]   = bz;
    }
    ((float4*)(pacc + (size_t)blk * DD))[t] = ((const float4*)sacc)[t];
}

// ---- kB: combine 128 block partials per batch -> normalized out2[b][d]
__global__ __launch_bounds__(256) void kB(const float* __restrict__ pmax,
                                          const float* __restrict__ pz,
                                          const float* __restrict__ pacc,
                                          float* __restrict__ out2) {
    int b = blockIdx.x, t = threadIdx.x;
    __shared__ float se[BPB];
    const float* pm = pmax + b * BPB;
    const float* pzb = pz + b * BPB;
    float m = -1e30f;
    for (int i = 0; i < BPB; ++i) m = fmaxf(m, pm[i]);     // broadcast loads, all threads same
    if (t < BPB) se[t] = __expf(pm[t] - m);
    __syncthreads();
    float Z = 0.f;
    for (int i = 0; i < BPB; ++i) Z = fmaf(pzb[i], se[i], Z);
    float invZ = 1.f / Z;

    const float4* P = (const float4*)pacc + (size_t)b * BPB * (DD / 4);
    float4 a = make_float4(0.f, 0.f, 0.f, 0.f);
    for (int i = 0; i < BPB; ++i) {
        float e = se[i];
        float4 v = P[(size_t)i * 256 + t];
        a.x = fmaf(e, v.x, a.x);
        a.y = fmaf(e, v.y, a.y);
        a.z = fmaf(e, v.z, a.z);
        a.w = fmaf(e, v.w, a.w);
    }
    a.x *= invZ; a.y *= invZ; a.z *= invZ; a.w *= invZ;
    ((float4*)(out2 + (size_t)b * DD))[t] = a;
}

// ---- kE: seg3 = out2 * o1 per row. No input reads; pure write stream.
__global__ __launch_bounds__(256) void kE(const float* __restrict__ memory,
                                          const float* __restrict__ att,
                                          const float* __restrict__ out2,
                                          float* __restrict__ out) {
    int blk = blockIdx.x;           // 2048: 256 chunks of 16 rows per batch
    int b = blk >> 8, chunk = blk & 255;
    int t = threadIdx.x;
    float4 m0 = ((const float4*)(memory + (size_t)b * 2 * DD))[t];
    float4 m1 = ((const float4*)(memory + (size_t)b * 2 * DD + DD))[t];
    float4 o2 = ((const float4*)(out2 + (size_t)b * DD))[t];
    const float2* attb = (const float2*)att + (size_t)b * LL + chunk * 16;
    for (int r = 0; r < 16; ++r) {
        float2 v = attb[r];
        float w0 = 1.f / (1.f + __expf(v.y - v.x));
        float w1 = 1.f - w0;
        float4 o1;
        o1.x = fmaf(w0, m0.x, w1 * m1.x);
        o1.y = fmaf(w0, m0.y, w1 * m1.y);
        o1.z = fmaf(w0, m0.z, w1 * m1.z);
        o1.w = fmaf(w0, m0.w, w1 * m1.w);
        float* orow = out + (size_t)(b * LL + chunk * 16 + r) * (4 * DD) + 3 * DD;
        ((float4*)orow)[t] = make_float4(o2.x * o1.x, o2.y * o1.y,
                                         o2.z * o1.z, o2.w * o1.w);
    }
}

extern "C" void kernel_launch(void* const* d_in, const int* in_sizes, int n_in,
                              void* d_out, int out_size, void* d_ws, size_t ws_size,
                              hipStream_t stream) {
    const float* input  = (const float*)d_in[0];   // [8,4096,1024] fp32
    const float* memory = (const float*)d_in[1];   // [8,2,1024] fp32
    const float* w_in   = (const float*)d_in[2];   // [1024] fp32
    const float* w_mem  = (const float*)d_in[3];   // [1024] fp32
    const float* ds     = (const float*)d_in[4];   // [1024] fp32
    float* out = (float*)d_out;                    // [8,4096,4096] fp32

    // workspace layout (floats):
    //   cvec 16384 | mdot 16 | att 65536 | pmax 1024 | pz 1024 | out2 8192 | pacc 1048576
    //   total ~4.6 MB
    float* ws    = (float*)d_ws;
    float* cvec  = ws;
    float* mdot  = ws + 16384;
    float* att   = ws + 16400;
    float* pmax  = ws + 81936;
    float* pz    = ws + 82960;
    float* out2  = ws + 83984;
    float* pacc  = ws + 92176;

    kP<<<16,   256, 0, stream>>>(memory, w_in, w_mem, ds, cvec, mdot);
    kA<<<1024, 256, 0, stream>>>(input, memory, cvec, mdot, att, pmax, pz, pacc, out);
    kB<<<BB,   256, 0, stream>>>(pmax, pz, pacc, out2);
    kE<<<2048, 256, 0, stream>>>(memory, att, out2, out);
}

// Round 3
// 664.347 us; speedup vs baseline: 1.0411x; 1.0411x over previous
//
#include <hip/hip_runtime.h>
#include <stdint.h>

// BiDAF co-attention, B=8, L=4096, D=1024, M=2. All FP32.
// 3-kernel minimal-traffic pipeline (non-cooperative, known-correct structure):
//   kA : ONE pass over input (NT loads). In-register weight fold.
//        Per row: att dots -> w0 (softmax over M=2) stored to w0buf;
//        seg0=x, seg1=o1, seg2=x*o1 written with NON-TEMPORAL stores;
//        online softmax-over-L accumulation -> per-block partials.
//   kB : combine 128 partials/batch -> normalized out2[b][d].
//   kE : seg3 = out2*o1 per row (reads w0buf/memory/out2 from L2; NT writes).
// HBM traffic: 134 MB read + 537 MB write + ~9 MB partials  (~structural minimum).

#define BB 8
#define LL 4096
#define DD 1024
#define NBLK 1024          // kA blocks
#define BPB 128            // kA blocks per batch
#define RPB 32             // rows per kA block
#define RPW 8              // rows per wave

typedef float f32x4 __attribute__((ext_vector_type(4)));

static __device__ __forceinline__ f32x4 nt_load4(const float* p) {
    return __builtin_nontemporal_load((const f32x4*)p);
}
static __device__ __forceinline__ void nt_store4(float* p, f32x4 v) {
    __builtin_nontemporal_store(v, (f32x4*)p);
}
static __device__ __forceinline__ float hsum4(f32x4 v) {
    return (v.x + v.y) + (v.z + v.w);
}

// ---- kA: single input pass. 1024 blocks (128/batch), 4 waves/block, 8 rows/wave.
__global__ __launch_bounds__(256) void kA(const float* __restrict__ input,
                                          const float* __restrict__ memory,
                                          const float* __restrict__ w_in,
                                          const float* __restrict__ w_mem,
                                          const float* __restrict__ ds,
                                          float* __restrict__ w0buf,
                                          float* __restrict__ pmax,
                                          float* __restrict__ pz,
                                          float* __restrict__ pacc,
                                          float* __restrict__ out) {
    int blk = blockIdx.x;          // 1024
    int b = blk >> 7, chunk = blk & 127;
    int t = threadIdx.x;
    int wave = t >> 6, lane = t & 63;

    // ---- prolog: fold weights in-register; mdot via butterfly
    f32x4 rc0[4], rc1[4], rm0[4], rm1[4], acc[4];
    float md0 = 0.f, md1 = 0.f;
    {
        const float* m0p = memory + (size_t)b * 2 * DD;
        const float* m1p = m0p + DD;
#pragma unroll
        for (int k = 0; k < 4; ++k) {
            int i = 4 * (lane + 64 * k);
            f32x4 m0 = *(const f32x4*)(m0p + i);
            f32x4 m1 = *(const f32x4*)(m1p + i);
            f32x4 wi = *(const f32x4*)(w_in + i);
            f32x4 dv = *(const f32x4*)(ds + i);
            f32x4 wm = *(const f32x4*)(w_mem + i);
            rm0[k] = m0; rm1[k] = m1;
            rc0[k] = wi + dv * m0;
            rc1[k] = wi + dv * m1;
            md0 += hsum4(m0 * wm);
            md1 += hsum4(m1 * wm);
            acc[k] = (f32x4)(0.f);
        }
        for (int off = 32; off; off >>= 1) {
            md0 += __shfl_xor(md0, off);
            md1 += __shfl_xor(md1, off);
        }
    }

    // ---- phase A: this block's 32 rows (8 per wave)
    float lmax = -1e30f, zsum = 0.f;
    int l0 = chunk * RPB + wave * RPW;
    const float* inb = input + (size_t)b * LL * DD;
    for (int r = 0; r < RPW; ++r) {
        int l = l0 + r;
        const float* row = inb + (size_t)l * DD;
        f32x4 x[4];
#pragma unroll
        for (int k = 0; k < 4; ++k) x[k] = nt_load4(row + 4 * (lane + 64 * k));

        f32x4 s0 = x[0] * rc0[0], s1 = x[0] * rc1[0];
#pragma unroll
        for (int k = 1; k < 4; ++k) { s0 += x[k] * rc0[k]; s1 += x[k] * rc1[k]; }
        float a0 = hsum4(s0), a1 = hsum4(s1);
        for (int off = 32; off; off >>= 1) {
            a0 += __shfl_xor(a0, off);
            a1 += __shfl_xor(a1, off);
        }
        a0 += md0; a1 += md1;

        float w0 = 1.f / (1.f + __expf(a1 - a0));   // softmax over M=2
        float w1 = 1.f - w0;
        if (lane == 0) w0buf[(size_t)b * LL + l] = w0;
        float ml = fmaxf(a0, a1);

        // online softmax over L (wave-uniform branch)
        float e;
        if (ml > lmax) {
            float s = __expf(lmax - ml);
            zsum *= s;
#pragma unroll
            for (int k = 0; k < 4; ++k) acc[k] *= s;
            lmax = ml;
            e = 1.f;
        } else {
            e = __expf(ml - lmax);
        }
        zsum += e;

        float* orow = out + (size_t)(b * LL + l) * (4 * DD);
#pragma unroll
        for (int k = 0; k < 4; ++k) {
            int i = 4 * (lane + 64 * k);
            f32x4 o1 = w0 * rm0[k] + w1 * rm1[k];
            nt_store4(orow + i, x[k]);                    // seg0
            nt_store4(orow + DD + i, o1);                 // seg1
            nt_store4(orow + 2 * DD + i, x[k] * o1);      // seg2
            acc[k] += e * x[k];
        }
    }

    // ---- block combine: conflict-free per-wave LDS slices
    __shared__ float swm[4], swz[4];
    __shared__ __align__(16) float swacc[4][DD];
    if (lane == 0) { swm[wave] = lmax; swz[wave] = zsum; }
    __syncthreads();
    float bmax = fmaxf(fmaxf(swm[0], swm[1]), fmaxf(swm[2], swm[3]));
    float f = __expf(lmax - bmax);
#pragma unroll
    for (int k = 0; k < 4; ++k) {
        *(f32x4*)(swacc[wave] + 4 * (lane + 64 * k)) = f * acc[k];
    }
    __syncthreads();
    {
        f32x4 s = *(const f32x4*)(swacc[0] + 4 * t) + *(const f32x4*)(swacc[1] + 4 * t)
                + *(const f32x4*)(swacc[2] + 4 * t) + *(const f32x4*)(swacc[3] + 4 * t);
        *(f32x4*)(pacc + (size_t)blk * DD + 4 * t) = s;
        if (t == 0) {
            float bz = 0.f;
#pragma unroll
            for (int w = 0; w < 4; ++w) bz += swz[w] * __expf(swm[w] - bmax);
            pmax[blk] = bmax;
            pz[blk]   = bz;
        }
    }
}

// ---- kB: combine 128 block partials per batch -> normalized out2[b][d]
__global__ __launch_bounds__(256) void kB(const float* __restrict__ pmax,
                                          const float* __restrict__ pz,
                                          const float* __restrict__ pacc,
                                          float* __restrict__ out2) {
    int b = blockIdx.x, t = threadIdx.x;
    __shared__ float se[BPB];
    const float* pm  = pmax + b * BPB;
    const float* pzb = pz   + b * BPB;
    float m = -1e30f;
    for (int i = 0; i < BPB; ++i) m = fmaxf(m, pm[i]);     // broadcast loads
    if (t < BPB) se[t] = __expf(pm[t] - m);
    __syncthreads();
    float Z = 0.f;
    for (int i = 0; i < BPB; ++i) Z = fmaf(pzb[i], se[i], Z);
    float invZ = 1.f / Z;

    const float* P = pacc + (size_t)b * BPB * DD;
    f32x4 a = (f32x4)(0.f);
    for (int i = 0; i < BPB; ++i) {
        a += se[i] * *(const f32x4*)(P + (size_t)i * DD + 4 * t);
    }
    a *= invZ;
    *(f32x4*)(out2 + (size_t)b * DD + 4 * t) = a;
}

// ---- kE: seg3 = out2 * o1 per row. Pure NT write stream.
__global__ __launch_bounds__(256) void kE(const float* __restrict__ memory,
                                          const float* __restrict__ w0buf,
                                          const float* __restrict__ out2,
                                          float* __restrict__ out) {
    int blk = blockIdx.x;           // 2048: 256 chunks of 16 rows per batch
    int b = blk >> 8, chunk = blk & 255;
    int t = threadIdx.x;
    f32x4 m0 = *(const f32x4*)(memory + (size_t)b * 2 * DD + 4 * t);
    f32x4 m1 = *(const f32x4*)(memory + (size_t)b * 2 * DD + DD + 4 * t);
    f32x4 o2 = *(const f32x4*)(out2 + (size_t)b * DD + 4 * t);
    const float* w0b = w0buf + (size_t)b * LL + chunk * 16;
    for (int r = 0; r < 16; ++r) {
        float w0 = w0b[r];
        float w1 = 1.f - w0;
        f32x4 o1 = w0 * m0 + w1 * m1;
        float* orow = out + (size_t)(b * LL + chunk * 16 + r) * (4 * DD) + 3 * DD;
        nt_store4(orow + 4 * t, o2 * o1);
    }
}

extern "C" void kernel_launch(void* const* d_in, const int* in_sizes, int n_in,
                              void* d_out, int out_size, void* d_ws, size_t ws_size,
                              hipStream_t stream) {
    const float* input  = (const float*)d_in[0];   // [8,4096,1024] fp32
    const float* memory = (const float*)d_in[1];   // [8,2,1024] fp32
    const float* w_in   = (const float*)d_in[2];   // [1024] fp32
    const float* w_mem  = (const float*)d_in[3];   // [1024] fp32
    const float* ds     = (const float*)d_in[4];   // [1024] fp32
    float* out = (float*)d_out;                    // [8,4096,4096] fp32

    // workspace (floats): w0buf 32768 | pmax 1024 | pz 1024 | out2 8192 | pacc 1048576
    float* ws    = (float*)d_ws;
    float* w0buf = ws;
    float* pmax  = ws + 32768;
    float* pz    = ws + 33792;
    float* out2  = ws + 34816;
    float* pacc  = ws + 43008;

    kA<<<NBLK, 256, 0, stream>>>(input, memory, w_in, w_mem, ds,
                                 w0buf, pmax, pz, pacc, out);
    kB<<<BB,   256, 0, stream>>>(pmax, pz, pacc, out2);
    kE<<<2048, 256, 0, stream>>>(memory, w0buf, out2, out);
}

// Round 4
// 646.709 us; speedup vs baseline: 1.0695x; 1.0273x over previous
//
#include <hip/hip_runtime.h>
#include <stdint.h>

// BiDAF co-attention, B=8, L=4096, D=1024, M=2. All FP32.
// 3-kernel minimal-HBM pipeline, tuned for memory-level parallelism:
//   kA : ONE pass over input (NT loads), 2048 blocks (256/batch, 4 rows/wave).
//        In-register weight fold. Per row: att dots -> w0 -> w0buf;
//        seg0|seg1|seg2 written segment-major (4KB contiguous burst per wave
//        per segment) with NT stores; online softmax-over-L -> per-block partials.
//   kB : 32 blocks (batch x 256-d slice) combine 256 partials/batch -> out2.
//   kE : 4096 blocks, seg3 = out2*o1 per row (pure NT write stream).
// Compulsory HBM traffic: 134 MB read + 537 MB write (+ ~12 MB partials).

#define BB 8
#define LL 4096
#define DD 1024
#define NBLK 2048          // kA blocks
#define BPB 256            // kA blocks per batch
#define RPB 16             // rows per kA block
#define RPW 4              // rows per wave

typedef float f32x4 __attribute__((ext_vector_type(4)));

static __device__ __forceinline__ f32x4 nt_load4(const float* p) {
    return __builtin_nontemporal_load((const f32x4*)p);
}
static __device__ __forceinline__ void nt_store4(float* p, f32x4 v) {
    __builtin_nontemporal_store(v, (f32x4*)p);
}
static __device__ __forceinline__ float hsum4(f32x4 v) {
    return (v.x + v.y) + (v.z + v.w);
}

// ---- kA: single input pass. 2048 blocks, 4 waves/block, 4 rows/wave.
__global__ __launch_bounds__(256) void kA(const float* __restrict__ input,
                                          const float* __restrict__ memory,
                                          const float* __restrict__ w_in,
                                          const float* __restrict__ w_mem,
                                          const float* __restrict__ ds,
                                          float* __restrict__ w0buf,
                                          float* __restrict__ pmax,
                                          float* __restrict__ pz,
                                          float* __restrict__ pacc,
                                          float* __restrict__ out) {
    int blk = blockIdx.x;          // 2048
    int b = blk >> 8, chunk = blk & 255;
    int t = threadIdx.x;
    int wave = t >> 6, lane = t & 63;

    // ---- prolog: fold weights in-register; mdot via butterfly
    f32x4 rc0[4], rc1[4], rm0[4], rm1[4], acc[4];
    float md0 = 0.f, md1 = 0.f;
    {
        const float* m0p = memory + (size_t)b * 2 * DD;
        const float* m1p = m0p + DD;
#pragma unroll
        for (int k = 0; k < 4; ++k) {
            int i = 4 * (lane + 64 * k);
            f32x4 m0 = *(const f32x4*)(m0p + i);
            f32x4 m1 = *(const f32x4*)(m1p + i);
            f32x4 wi = *(const f32x4*)(w_in + i);
            f32x4 dv = *(const f32x4*)(ds + i);
            f32x4 wm = *(const f32x4*)(w_mem + i);
            rm0[k] = m0; rm1[k] = m1;
            rc0[k] = wi + dv * m0;
            rc1[k] = wi + dv * m1;
            md0 += hsum4(m0 * wm);
            md1 += hsum4(m1 * wm);
            acc[k] = (f32x4)(0.f);
        }
        for (int off = 32; off; off >>= 1) {
            md0 += __shfl_xor(md0, off);
            md1 += __shfl_xor(md1, off);
        }
    }

    // ---- phase A: this block's 16 rows (4 per wave)
    float lmax = -1e30f, zsum = 0.f;
    int l0 = chunk * RPB + wave * RPW;
    const float* inb = input + (size_t)b * LL * DD;
    for (int r = 0; r < RPW; ++r) {
        int l = l0 + r;
        const float* row = inb + (size_t)l * DD;
        f32x4 x[4];
#pragma unroll
        for (int k = 0; k < 4; ++k) x[k] = nt_load4(row + 4 * (lane + 64 * k));

        f32x4 s0 = x[0] * rc0[0], s1 = x[0] * rc1[0];
#pragma unroll
        for (int k = 1; k < 4; ++k) { s0 += x[k] * rc0[k]; s1 += x[k] * rc1[k]; }
        float a0 = hsum4(s0), a1 = hsum4(s1);
        for (int off = 32; off; off >>= 1) {
            a0 += __shfl_xor(a0, off);
            a1 += __shfl_xor(a1, off);
        }
        a0 += md0; a1 += md1;

        float w0 = 1.f / (1.f + __expf(a1 - a0));   // softmax over M=2
        float w1 = 1.f - w0;
        if (lane == 0) w0buf[(size_t)b * LL + l] = w0;
        float ml = fmaxf(a0, a1);

        // online softmax over L (wave-uniform branch)
        float e;
        if (ml > lmax) {
            float s = __expf(lmax - ml);
            zsum *= s;
#pragma unroll
            for (int k = 0; k < 4; ++k) acc[k] *= s;
            lmax = ml;
            e = 1.f;
        } else {
            e = __expf(ml - lmax);
        }
        zsum += e;

        // segment-major stores: 4KB contiguous burst per wave per segment
        float* orow = out + (size_t)(b * LL + l) * (4 * DD);
        f32x4 o1v[4];
#pragma unroll
        for (int k = 0; k < 4; ++k) o1v[k] = w0 * rm0[k] + w1 * rm1[k];
#pragma unroll
        for (int k = 0; k < 4; ++k)
            nt_store4(orow + 4 * (lane + 64 * k), x[k]);                     // seg0
#pragma unroll
        for (int k = 0; k < 4; ++k)
            nt_store4(orow + DD + 4 * (lane + 64 * k), o1v[k]);              // seg1
#pragma unroll
        for (int k = 0; k < 4; ++k)
            nt_store4(orow + 2 * DD + 4 * (lane + 64 * k), x[k] * o1v[k]);   // seg2
#pragma unroll
        for (int k = 0; k < 4; ++k) acc[k] += e * x[k];
    }

    // ---- block combine: conflict-free per-wave LDS slices
    __shared__ float swm[4], swz[4];
    __shared__ __align__(16) float swacc[4][DD];
    if (lane == 0) { swm[wave] = lmax; swz[wave] = zsum; }
    __syncthreads();
    float bmax = fmaxf(fmaxf(swm[0], swm[1]), fmaxf(swm[2], swm[3]));
    float f = __expf(lmax - bmax);
#pragma unroll
    for (int k = 0; k < 4; ++k) {
        *(f32x4*)(swacc[wave] + 4 * (lane + 64 * k)) = f * acc[k];
    }
    __syncthreads();
    {
        f32x4 s = *(const f32x4*)(swacc[0] + 4 * t) + *(const f32x4*)(swacc[1] + 4 * t)
                + *(const f32x4*)(swacc[2] + 4 * t) + *(const f32x4*)(swacc[3] + 4 * t);
        *(f32x4*)(pacc + (size_t)blk * DD + 4 * t) = s;
        if (t == 0) {
            float bz = 0.f;
#pragma unroll
            for (int w = 0; w < 4; ++w) bz += swz[w] * __expf(swm[w] - bmax);
            pmax[blk] = bmax;
            pz[blk]   = bz;
        }
    }
}

// ---- kB: 32 blocks (batch x 256-d slice) combine 256 partials/batch -> out2
__global__ __launch_bounds__(256) void kB(const float* __restrict__ pmax,
                                          const float* __restrict__ pz,
                                          const float* __restrict__ pacc,
                                          float* __restrict__ out2) {
    int bid = blockIdx.x;           // 32
    int b = bid >> 2, q = bid & 3;
    int t = threadIdx.x;
    int d = q * 256 + t;
    __shared__ float se[BPB];
    const float* pm  = pmax + b * BPB;
    const float* pzb = pz   + b * BPB;
    float m = -1e30f;
    for (int i = 0; i < BPB; ++i) m = fmaxf(m, pm[i]);     // broadcast loads
    se[t] = __expf(pm[t] - m);
    __syncthreads();
    float Z = 0.f;
    for (int i = 0; i < BPB; ++i) Z = fmaf(pzb[i], se[i], Z);
    float invZ = 1.f / Z;

    const float* P = pacc + (size_t)b * BPB * DD + d;
    float a = 0.f;
    for (int i = 0; i < BPB; ++i) a = fmaf(se[i], P[(size_t)i * DD], a);
    out2[(size_t)b * DD + d] = a * invZ;
}

// ---- kE: seg3 = out2 * o1 per row. Pure NT write stream. 4096 blocks x 8 rows.
__global__ __launch_bounds__(256) void kE(const float* __restrict__ memory,
                                          const float* __restrict__ w0buf,
                                          const float* __restrict__ out2,
                                          float* __restrict__ out) {
    int bid = blockIdx.x;           // 4096
    int b = bid >> 9, chunk = bid & 511;
    int t = threadIdx.x;
    f32x4 m0 = *(const f32x4*)(memory + (size_t)b * 2 * DD + 4 * t);
    f32x4 m1 = *(const f32x4*)(memory + (size_t)b * 2 * DD + DD + 4 * t);
    f32x4 o2 = *(const f32x4*)(out2 + (size_t)b * DD + 4 * t);
    const float* w0b = w0buf + (size_t)b * LL + chunk * 8;
    for (int r = 0; r < 8; ++r) {
        float w0 = w0b[r];
        float w1 = 1.f - w0;
        f32x4 o1 = w0 * m0 + w1 * m1;
        float* orow = out + (size_t)(b * LL + chunk * 8 + r) * (4 * DD) + 3 * DD;
        nt_store4(orow + 4 * t, o2 * o1);
    }
}

extern "C" void kernel_launch(void* const* d_in, const int* in_sizes, int n_in,
                              void* d_out, int out_size, void* d_ws, size_t ws_size,
                              hipStream_t stream) {
    const float* input  = (const float*)d_in[0];   // [8,4096,1024] fp32
    const float* memory = (const float*)d_in[1];   // [8,2,1024] fp32
    const float* w_in   = (const float*)d_in[2];   // [1024] fp32
    const float* w_mem  = (const float*)d_in[3];   // [1024] fp32
    const float* ds     = (const float*)d_in[4];   // [1024] fp32
    float* out = (float*)d_out;                    // [8,4096,4096] fp32

    // workspace (floats): w0buf 32768 | pmax 2048 | pz 2048 | out2 8192 | pacc 2M (~8.6 MB)
    float* ws    = (float*)d_ws;
    float* w0buf = ws;
    float* pmax  = ws + 32768;
    float* pz    = ws + 34816;
    float* out2  = ws + 36864;
    float* pacc  = ws + 45056;

    kA<<<NBLK, 256, 0, stream>>>(input, memory, w_in, w_mem, ds,
                                 w0buf, pmax, pz, pacc, out);
    kB<<<32,   256, 0, stream>>>(pmax, pz, pacc, out2);
    kE<<<4096, 256, 0, stream>>>(memory, w0buf, out2, out);
}